// Round 1
// baseline (439.699 us; speedup 1.0000x reference)
//
#include <hip/hip_runtime.h>

#define N_TOK 8192
#define DDIM 1024
#define ODIM 1024
#define NEXP 8

typedef __attribute__((ext_vector_type(8))) short bf16x8;
typedef __attribute__((ext_vector_type(4))) float f32x4;

__device__ __forceinline__ unsigned int f2bf(float f) {
    unsigned int u = __float_as_uint(f);
    return (u + 0x7fffu + ((u >> 16) & 1u)) >> 16;  // RNE
}

// ---------------- We [E,D,O] fp32 -> WeT [E,O,D] bf16 ----------------
__global__ __launch_bounds__(256) void wet_kernel(const float* __restrict__ We,
                                                  unsigned short* __restrict__ WeT) {
    __shared__ float tile[64][65];
    const int e = blockIdx.z, d0 = blockIdx.x * 64, o0 = blockIdx.y * 64;
    const int tid = threadIdx.x;
#pragma unroll
    for (int p = 0; p < 4; ++p) {
        int idx = p * 256 + tid;
        int row = idx >> 4, c = idx & 15;  // row: d-local, c: float4 within o
        float4 v = *(const float4*)&We[(((size_t)e * 1024 + d0 + row) << 10) + o0 + (c << 2)];
        tile[row][c * 4 + 0] = v.x; tile[row][c * 4 + 1] = v.y;
        tile[row][c * 4 + 2] = v.z; tile[row][c * 4 + 3] = v.w;
    }
    __syncthreads();
#pragma unroll
    for (int p = 0; p < 2; ++p) {
        int idx = p * 256 + tid;
        int orow = idx >> 3, c8 = idx & 7;  // orow: o-local, c8: 8-elem chunk along d
        unsigned int u[8];
#pragma unroll
        for (int j = 0; j < 8; ++j) u[j] = f2bf(tile[c8 * 8 + j][orow]);
        uint4 q;
        q.x = u[0] | (u[1] << 16); q.y = u[2] | (u[3] << 16);
        q.z = u[4] | (u[5] << 16); q.w = u[6] | (u[7] << 16);
        *(uint4*)&WeT[(((size_t)e * 1024 + o0 + orow) << 10) + d0 + (c8 << 3)] = q;
    }
}

// ---------------- gating: logits, top-2, renorm, bucket scatter ----------------
__global__ __launch_bounds__(256) void gate_kernel(const float* __restrict__ x,
                                                   const float* __restrict__ Wg,
                                                   const float* __restrict__ bg,
                                                   int* __restrict__ counts,
                                                   int* __restrict__ btok,
                                                   float* __restrict__ bgate) {
    const int wave = threadIdx.x >> 6, lane = threadIdx.x & 63;
    const int tbase = blockIdx.x * 64 + wave * 16;
    for (int i = 0; i < 16; ++i) {
        const int t = tbase + i;
        const float* xr = x + (size_t)t * DDIM;
        float acc[8] = {0, 0, 0, 0, 0, 0, 0, 0};
#pragma unroll
        for (int it = 0; it < 16; ++it) {
            int d = it * 64 + lane;
            float xv = xr[d];
            const float4* w = (const float4*)(Wg + d * 8);
            float4 w0 = w[0], w1 = w[1];
            acc[0] += xv * w0.x; acc[1] += xv * w0.y; acc[2] += xv * w0.z; acc[3] += xv * w0.w;
            acc[4] += xv * w1.x; acc[5] += xv * w1.y; acc[6] += xv * w1.z; acc[7] += xv * w1.w;
        }
#pragma unroll
        for (int off = 32; off > 0; off >>= 1) {
#pragma unroll
            for (int j = 0; j < 8; ++j) acc[j] += __shfl_xor(acc[j], off, 64);
        }
        if (lane == 0) {
            float s[8];
#pragma unroll
            for (int e = 0; e < 8; ++e) s[e] = acc[e] + bg[e];
            int a = 0;
#pragma unroll
            for (int e = 1; e < 8; ++e) if (s[e] > s[a]) a = e;
            int b = (a == 0) ? 1 : 0;
#pragma unroll
            for (int e = 0; e < 8; ++e) if (e != a && e != b && s[e] > s[b]) b = e;
            // renormalized top-2 softmax == sigmoid of logit gap (denominator cancels)
            float g0 = 1.0f / (1.0f + __expf(s[b] - s[a]));
            float g1 = 1.0f - g0;
            int p0 = atomicAdd(&counts[a], 1);
            btok[a * N_TOK + p0] = t; bgate[a * N_TOK + p0] = g0;
            int p1 = atomicAdd(&counts[b], 1);
            btok[b * N_TOK + p1] = t; bgate[b * N_TOK + p1] = g1;
        }
    }
}

// ---------------- grouped expert GEMM, 128x128 tile, BK=32, bf16 MFMA ----------------
__global__ __launch_bounds__(256) void moe_gemm(const float* __restrict__ x,
                                                const unsigned short* __restrict__ WeT,
                                                const float* __restrict__ be,
                                                const int* __restrict__ counts,
                                                const int* __restrict__ btok,
                                                const float* __restrict__ bgate,
                                                float* __restrict__ out) {
    const int e = blockIdx.z;
    const int cnt = counts[e];
    const int r0 = blockIdx.y * 128;
    if (r0 >= cnt) return;
    const int n0 = blockIdx.x * 128;

    __shared__ unsigned short sA[128 * 40];  // [token-row][k] bf16, row pad 40
    __shared__ unsigned short sB[128 * 40];  // [o-row][k] bf16
    __shared__ int s_tok[128];
    __shared__ float s_gate[128];

    const int tid = threadIdx.x;
    if (tid < 128) {
        int r = r0 + tid;
        int rc = (r < cnt) ? r : (cnt - 1);
        s_tok[tid] = btok[e * N_TOK + rc];
        s_gate[tid] = (r < cnt) ? bgate[e * N_TOK + r] : 0.0f;
    }

    const int wave = tid >> 6, lane = tid & 63;
    const int wm = (wave >> 1) * 64, wn = (wave & 1) * 64;
    const int quad = lane >> 4, rA = lane & 15;
    const int qk = quad * 8;

    f32x4 acc[4][4];
#pragma unroll
    for (int mi = 0; mi < 4; ++mi)
#pragma unroll
        for (int ni = 0; ni < 4; ++ni) acc[mi][ni] = (f32x4){0.f, 0.f, 0.f, 0.f};

    __syncthreads();  // s_tok/s_gate ready

    for (int kb = 0; kb < DDIM; kb += 32) {
        // stage A: 128 rows x 32 floats (gathered token rows, fp32 -> bf16)
#pragma unroll
        for (int p = 0; p < 4; ++p) {
            int idx = p * 256 + tid;
            int row = idx >> 3, c4 = idx & 7;
            float4 v = *(const float4*)&x[(size_t)s_tok[row] * DDIM + kb + (c4 << 2)];
            uint2 w;
            w.x = f2bf(v.x) | (f2bf(v.y) << 16);
            w.y = f2bf(v.z) | (f2bf(v.w) << 16);
            *(uint2*)&sA[row * 40 + (c4 << 2)] = w;
        }
        // stage B: 128 o-rows x 32 bf16 from WeT
#pragma unroll
        for (int p = 0; p < 2; ++p) {
            int idx = p * 256 + tid;
            int row = idx >> 2, c8 = idx & 3;
            uint4 v = *(const uint4*)&WeT[(((size_t)e * 1024 + n0 + row) << 10) + kb + (c8 << 3)];
            *(uint4*)&sB[row * 40 + (c8 << 3)] = v;
        }
        __syncthreads();

        bf16x8 af[4], bf[4];
#pragma unroll
        for (int mi = 0; mi < 4; ++mi) af[mi] = *(bf16x8*)&sA[(wm + mi * 16 + rA) * 40 + qk];
#pragma unroll
        for (int ni = 0; ni < 4; ++ni) bf[ni] = *(bf16x8*)&sB[(wn + ni * 16 + rA) * 40 + qk];
#pragma unroll
        for (int mi = 0; mi < 4; ++mi)
#pragma unroll
            for (int ni = 0; ni < 4; ++ni)
                acc[mi][ni] = __builtin_amdgcn_mfma_f32_16x16x32_bf16(af[mi], bf[ni], acc[mi][ni], 0, 0, 0);
        __syncthreads();
    }

    // epilogue: D[row = quad*4+reg][col = lane&15]; bias + gate, atomic add
#pragma unroll
    for (int ni = 0; ni < 4; ++ni) {
        int col = n0 + wn + ni * 16 + rA;
        float bias = be[(e << 10) + col];
#pragma unroll
        for (int mi = 0; mi < 4; ++mi) {
#pragma unroll
            for (int r = 0; r < 4; ++r) {
                int lrow = wm + mi * 16 + quad * 4 + r;
                if (r0 + lrow < cnt) {
                    float v = (acc[mi][ni][r] + bias) * s_gate[lrow];
                    atomicAdd(out + (size_t)s_tok[lrow] * ODIM + col, v);
                }
            }
        }
    }
}

extern "C" void kernel_launch(void* const* d_in, const int* in_sizes, int n_in,
                              void* d_out, int out_size, void* d_ws, size_t ws_size,
                              hipStream_t stream) {
    const float* x  = (const float*)d_in[0];
    const float* We = (const float*)d_in[1];
    const float* be = (const float*)d_in[2];
    const float* Wg = (const float*)d_in[3];
    const float* bg = (const float*)d_in[4];
    float* out = (float*)d_out;

    char* ws = (char*)d_ws;
    int* counts = (int*)ws;                                   // 8 ints (256 B slot)
    int* btok   = (int*)(ws + 256);                           // 8*8192*4 = 256 KB
    float* bgate = (float*)(ws + 256 + 8 * N_TOK * 4);        // 256 KB
    unsigned short* WeT = (unsigned short*)(ws + 256 + 2 * 8 * N_TOK * 4);  // 16.78 MB

    hipMemsetAsync(counts, 0, 8 * sizeof(int), stream);
    hipMemsetAsync(d_out, 0, (size_t)out_size * sizeof(float), stream);

    wet_kernel<<<dim3(16, 16, 8), 256, 0, stream>>>(We, WeT);
    gate_kernel<<<dim3(N_TOK / 64), 256, 0, stream>>>(x, Wg, bg, counts, btok, bgate);
    moe_gemm<<<dim3(ODIM / 128, N_TOK / 128, NEXP), 256, 0, stream>>>(x, WeT, be, counts, btok, bgate, out);
}